// Round 2
// baseline (437.633 us; speedup 1.0000x reference)
//
#include <hip/hip_runtime.h>
#include <hip/hip_bf16.h>

// AVWGCN: B=64, N=8192, Din=Dout=64, D=10, C=4, NPC=2048
// Pass 1 (k_sumEH): sum_EH[b,d,i] = sum_nodes relu(E[node,d])*mask[b,node] * x[b,node,i]
//   - LDS-staged indices/tEm, float4 x loads (1KB/wave-instr), pk-fma, shfl reduce, atomics.
// Pass 2 (k_main): per node: W = E@Wp (bf16 LDS [g][o][i] pad 80), Z = x*m + tE@sum_EH (bf16 LDS),
//   out = Z@W + E@bias via mfma_f32_16x16x32_bf16 (layout verified in round 1).

#define BB 64
#define NN 8192
#define DI 64
#define DO 64
#define DD 10
#define CC 4
#define NPC 2048

typedef __bf16 bf16;
typedef __bf16 bf16x8 __attribute__((ext_vector_type(8)));
typedef __bf16 bf16x4 __attribute__((ext_vector_type(4)));
typedef float f32x4 __attribute__((ext_vector_type(4)));

// ---------------- Kernel 1: sum_EH ----------------
// grid = 64 b * 16 chunks (512 nodes each), block = 256 (4 waves)
__global__ __launch_bounds__(256) void k_sumEH(
    const float* __restrict__ x, const float* __restrict__ emb,
    const float* __restrict__ mask, const int* __restrict__ np,
    float* __restrict__ sEH) {
  __shared__ int np_l[512];
  __shared__ float mask_l[512];
  __shared__ float tEm[512][DD];                 // relu(E)*mask, 20 KB
  __shared__ __align__(16) float red[4][DD][64]; // 10 KB

  const int b = blockIdx.x >> 4;
  const int chunk = blockIdx.x & 15;
  const int tid = threadIdx.x;
  const int lane = tid & 63;
  const int w = tid >> 6;

  // --- stage node ids + mask ---
  for (int s = tid; s < 512; s += 256) {
    const int node = np[chunk * 512 + s];
    np_l[s] = node;
    mask_l[s] = mask[(size_t)b * NN + node];
  }
  __syncthreads();
  // --- stage tEm = relu(emb)*mask ---
  for (int s = tid; s < 2560; s += 256) {
    const int nl = s / 5, pr = s % 5;
    const float2 e = *(const float2*)(emb + (size_t)np_l[nl] * DD + pr * 2);
    const float m = mask_l[nl];
    tEm[nl][pr * 2] = fmaxf(e.x, 0.f) * m;
    tEm[nl][pr * 2 + 1] = fmaxf(e.y, 0.f) * m;
  }
  __syncthreads();

  // --- main loop: wave w owns 128 nodes; per group, 4 nodes x 64 i (float4/lane) ---
  const int qq = lane >> 4, r16 = lane & 15;
  const f32x4* x4 = (const f32x4*)(x + (size_t)b * NN * DI);
  f32x4 acc[DD];
#pragma unroll
  for (int d = 0; d < DD; ++d) acc[d] = (f32x4)0.f;

  const int wbase = w * 128;
#pragma unroll 4
  for (int g = 0; g < 32; ++g) {
    const int nl = wbase + g * 4 + qq;
    const int node = np_l[nl];
    const f32x4 xv = x4[(size_t)node * 16 + r16];
#pragma unroll
    for (int d = 0; d < DD; ++d) {
      acc[d] += xv * tEm[nl][d];
    }
  }

  // --- reduce across the 4 node-groups (lanes l, l^16, l^32, l^48) ---
#pragma unroll
  for (int d = 0; d < DD; ++d) {
    f32x4 a = acc[d];
#pragma unroll
    for (int j = 0; j < 4; ++j) {
      float v = a[j];
      v += __shfl_xor(v, 16);
      v += __shfl_xor(v, 32);
      a[j] = v;
    }
    acc[d] = a;
  }
  if (qq == 0) {
#pragma unroll
    for (int d = 0; d < DD; ++d) *(f32x4*)&red[w][d][r16 * 4] = acc[d];
  }
  __syncthreads();

  for (int s = tid; s < DD * 64; s += 256) {
    const int d = s >> 6, i = s & 63;
    const float v = red[0][d][i] + red[1][d][i] + red[2][d][i] + red[3][d][i];
    atomicAdd(sEH + ((size_t)b * DD + d) * 64 + i, v);
  }
}

// ---------------- Kernel 2: main ----------------
// grid = N/4 = 2048 blocks, block = 256 (4 waves). Each block: 4 nodes (same client).
__global__ __launch_bounds__(256) void k_main(
    const float* __restrict__ x, const float* __restrict__ emb,
    const float* __restrict__ mask, const float* __restrict__ wp,
    const float* __restrict__ bp, const int* __restrict__ np,
    const float* __restrict__ sEH, float* __restrict__ out) {
  __shared__ float E_l[4][DD];
  __shared__ float tE_l[4][DD];
  __shared__ float bb_l[4][64];
  __shared__ float mask_l[64][4];
  __shared__ int node_l[4];
  __shared__ __align__(16) bf16 Wt[4][64][80];  // [g][o][i], stride 160B (8 touches/bank min)
  __shared__ __align__(16) bf16 Zl[16][4][80];  // [b_loc][g][i]

  const int tid = threadIdx.x;
  const int lane = tid & 63;
  const int w = tid >> 6;
  const int p0 = blockIdx.x * 4;  // output position base
  const int c = p0 >> 11;         // client (NPC=2048)

  // Phase 0: node ids / E / tE / mask staging
  if (tid < 4) node_l[tid] = np[p0 + tid];
  if (tid < 40) {
    const int g = tid / 10, d = tid % 10;
    const float e = emb[(size_t)np[p0 + g] * DD + d];
    E_l[g][d] = e;
    tE_l[g][d] = fmaxf(e, 0.f);
  }
  {
    const int bq = tid >> 2, g = tid & 3;
    mask_l[bq][g] = mask[(size_t)bq * NN + np[p0 + g]];
  }
  __syncthreads();

  // bias: bb_l[g=w][o=lane] = sum_d E[g][d]*bp[c,d,o]
  {
    float acc = 0.f;
#pragma unroll
    for (int d = 0; d < DD; ++d)
      acc = fmaf(E_l[w][d], bp[((size_t)(c * DD + d)) * DO + lane], acc);
    bb_l[w][lane] = acc;
  }

  // Phase 1: W build. wave w owns i in [w*16, w*16+16), lane = o; all 4 g at once (pk-fma).
  {
    f32x4 accW[16];
#pragma unroll
    for (int p = 0; p < 16; ++p) accW[p] = (f32x4)0.f;
#pragma unroll
    for (int d = 0; d < DD; ++d) {
      f32x4 ev;
      ev[0] = E_l[0][d]; ev[1] = E_l[1][d]; ev[2] = E_l[2][d]; ev[3] = E_l[3][d];
      const float* wrow = wp + ((size_t)(c * DD + d) * DI + w * 16) * DO + lane;
#pragma unroll
      for (int p = 0; p < 16; ++p) accW[p] += ev * wrow[(size_t)p * DO];
    }
#pragma unroll
    for (int g = 0; g < 4; ++g) {
      bf16x8 v0, v1;
#pragma unroll
      for (int p = 0; p < 8; ++p) { v0[p] = (bf16)accW[p][g]; v1[p] = (bf16)accW[p + 8][g]; }
      *(bf16x8*)&Wt[g][lane][w * 16] = v0;
      *(bf16x8*)&Wt[g][lane][w * 16 + 8] = v1;
    }
  }

  const int gq = lane >> 4, i4 = lane & 15;
  const f32x4* x4 = (const f32x4*)x;
  const f32x4* s4 = (const f32x4*)sEH;

  // Phase 2: 4 chunks of 16 batch rows
  for (int chunk = 0; chunk < 4; ++chunk) {
    // --- Z build: lane covers (g=gq, i=i4*4..+4); wave w covers b_loc = w*4..+4 ---
#pragma unroll
    for (int bb4 = 0; bb4 < 4; ++bb4) {
      const int b_loc = w * 4 + bb4;
      const int b = chunk * 16 + b_loc;
      const int nd = node_l[gq];
      f32x4 z = x4[((size_t)b * NN + nd) * 16 + i4];
      z *= mask_l[b][gq];
      const f32x4* sb = s4 + (size_t)b * DD * 16 + i4;
#pragma unroll
      for (int d = 0; d < DD; ++d) z += sb[d * 16] * tE_l[gq][d];
      bf16x4 zb;
#pragma unroll
      for (int j = 0; j < 4; ++j) zb[j] = (bf16)z[j];
      *(bf16x4*)&Zl[b_loc][gq][i4 * 4] = zb;
    }
    __syncthreads();

    // --- matmul: wave w = node g; 16x16x32 MFMA, 1 m-tile x 4 n-tiles x 2 k-tiles ---
    {
      const int g = w;
      const int q = lane >> 4, r16 = lane & 15;
      f32x4 acc[4];
#pragma unroll
      for (int nt = 0; nt < 4; ++nt) {
        const float bv = bb_l[g][nt * 16 + r16];
        acc[nt][0] = bv; acc[nt][1] = bv; acc[nt][2] = bv; acc[nt][3] = bv;
      }
#pragma unroll
      for (int kt = 0; kt < 2; ++kt) {
        const int k0 = kt * 32 + q * 8;  // contiguous-8 per lane (verified round 1)
        const bf16x8 a = *(const bf16x8*)&Zl[r16][g][k0];
#pragma unroll
        for (int nt = 0; nt < 4; ++nt) {
          const bf16x8 bfr = *(const bf16x8*)&Wt[g][nt * 16 + r16][k0];
          acc[nt] = __builtin_amdgcn_mfma_f32_16x16x32_bf16(a, bfr, acc[nt], 0, 0, 0);
        }
      }
      // epilogue: D row = 4q+r (b_loc), col = r16 (o within n-tile)
      const size_t pg = (size_t)(p0 + g);
#pragma unroll
      for (int nt = 0; nt < 4; ++nt) {
#pragma unroll
        for (int r = 0; r < 4; ++r) {
          const int bg = chunk * 16 + q * 4 + r;
          out[((size_t)bg * NN + pg) * DO + nt * 16 + r16] = acc[nt][r];
        }
      }
    }
    __syncthreads();
  }
}

extern "C" void kernel_launch(void* const* d_in, const int* in_sizes, int n_in,
                              void* d_out, int out_size, void* d_ws, size_t ws_size,
                              hipStream_t stream) {
  const float* x    = (const float*)d_in[0];
  const float* emb  = (const float*)d_in[1];
  // d_in[2] = poly_coefficients (unused in sprtrelu mode)
  const float* mask = (const float*)d_in[3];
  const float* wp   = (const float*)d_in[4];
  const float* bp   = (const float*)d_in[5];
  const int*   np   = (const int*)d_in[6];
  float* out = (float*)d_out;
  float* sEH = (float*)d_ws;  // [64][10][64] f32 = 160 KB

  hipMemsetAsync(sEH, 0, (size_t)BB * DD * 64 * sizeof(float), stream);
  k_sumEH<<<dim3(BB * 16), dim3(256), 0, stream>>>(x, emb, mask, np, sEH);
  k_main<<<dim3(NN / 4), dim3(256), 0, stream>>>(x, emb, mask, wp, bp, np, sEH, out);
}

// Round 3
// 426.826 us; speedup vs baseline: 1.0253x; 1.0253x over previous
//
#include <hip/hip_runtime.h>
#include <hip/hip_bf16.h>

// AVWGCN: B=64, N=8192, Din=Dout=64, D=10, C=4, NPC=2048
// k1: sum_EH[b,d,i] = sum_n relu(E[n,d])*mask[b,n]*x[b,n,i]; latency-pipelined stream of x.
// k2: one wave = one node; W/bias in regs+LDS (one barrier), barrier-free main loop;
//     z built in registers directly in MFMA A-frag layout; mfma_f32_16x16x32_bf16.

#define BB 64
#define NN 8192
#define DD 10
#define CC 4

typedef __bf16 bf16;
typedef __bf16 bf16x8 __attribute__((ext_vector_type(8)));
typedef float f32x4 __attribute__((ext_vector_type(4)));

// ---------------- Kernel 1: sum_EH ----------------
// grid = 64 b * 16 chunks (512 nodes each), block = 256 (4 waves)
__global__ __launch_bounds__(256, 4) void k_sumEH(
    const float* __restrict__ x, const float* __restrict__ emb,
    const float* __restrict__ mask, const int* __restrict__ np,
    float* __restrict__ sEH) {
  __shared__ int np_l[512];
  __shared__ float mask_l[512];
  __shared__ __align__(8) float tEm[512][DD];    // relu(E)*mask
  __shared__ __align__(16) float red[4][DD][64];

  const int b = blockIdx.x >> 4;
  const int chunk = blockIdx.x & 15;
  const int tid = threadIdx.x;
  const int lane = tid & 63;
  const int w = tid >> 6;

  for (int s = tid; s < 512; s += 256) {
    const int node = np[chunk * 512 + s];
    np_l[s] = node;
    mask_l[s] = mask[(size_t)b * NN + node];
  }
  __syncthreads();
  for (int s = tid; s < 2560; s += 256) {
    const int nl = s / 5, pr = s % 5;
    const float2 e = *(const float2*)(emb + (size_t)np_l[nl] * DD + pr * 2);
    const float m = mask_l[nl];
    tEm[nl][pr * 2] = fmaxf(e.x, 0.f) * m;
    tEm[nl][pr * 2 + 1] = fmaxf(e.y, 0.f) * m;
  }
  __syncthreads();

  const int qq = lane >> 4, r16 = lane & 15;
  const f32x4* x4 = (const f32x4*)(x + (size_t)b * NN * 64);
  f32x4 acc[DD];
#pragma unroll
  for (int d = 0; d < DD; ++d) acc[d] = (f32x4)0.f;

  const int wbase = w * 128;  // this wave: 32 groups of 4 nodes; 8 steps x batch 4

  int idA[4], idB[4];
  f32x4 xvA[4], xvB[4];

#define LOAD_IDS(buf, s_)                                        \
  _Pragma("unroll") for (int t = 0; t < 4; ++t)                  \
      buf[t] = np_l[wbase + ((s_) * 4 + t) * 4 + qq];
#define LOAD_X(bufx, bufi)                                       \
  _Pragma("unroll") for (int t = 0; t < 4; ++t)                  \
      bufx[t] = x4[(size_t)bufi[t] * 16 + r16];
#define FMA_BATCH(bufx, s_)                                      \
  _Pragma("unroll") for (int t = 0; t < 4; ++t) {                \
    const int nl = wbase + ((s_) * 4 + t) * 4 + qq;              \
    const float2 t01 = *(const float2*)&tEm[nl][0];              \
    const float2 t23 = *(const float2*)&tEm[nl][2];              \
    const float2 t45 = *(const float2*)&tEm[nl][4];              \
    const float2 t67 = *(const float2*)&tEm[nl][6];              \
    const float2 t89 = *(const float2*)&tEm[nl][8];              \
    const f32x4 xv = bufx[t];                                    \
    acc[0] += xv * t01.x; acc[1] += xv * t01.y;                  \
    acc[2] += xv * t23.x; acc[3] += xv * t23.y;                  \
    acc[4] += xv * t45.x; acc[5] += xv * t45.y;                  \
    acc[6] += xv * t67.x; acc[7] += xv * t67.y;                  \
    acc[8] += xv * t89.x; acc[9] += xv * t89.y;                  \
  }

  LOAD_IDS(idA, 0)
  LOAD_X(xvA, idA)
#pragma unroll
  for (int ss = 0; ss < 4; ++ss) {
    // step 2*ss uses A; prefetch B for step 2*ss+1
    LOAD_IDS(idB, 2 * ss + 1)
    LOAD_X(xvB, idB)
    FMA_BATCH(xvA, 2 * ss)
    if (ss < 3) {
      LOAD_IDS(idA, 2 * ss + 2)
      LOAD_X(xvA, idA)
    }
    FMA_BATCH(xvB, 2 * ss + 1)
  }
#undef LOAD_IDS
#undef LOAD_X
#undef FMA_BATCH

  // reduce across the 4 qq-groups (lanes l, l^16, l^32, l^48)
#pragma unroll
  for (int d = 0; d < DD; ++d) {
    f32x4 a = acc[d];
#pragma unroll
    for (int j = 0; j < 4; ++j) {
      float v = a[j];
      v += __shfl_xor(v, 16);
      v += __shfl_xor(v, 32);
      a[j] = v;
    }
    acc[d] = a;
  }
  if (qq == 0) {
#pragma unroll
    for (int d = 0; d < DD; ++d) *(f32x4*)&red[w][d][r16 * 4] = acc[d];
  }
  __syncthreads();

  for (int s = tid; s < DD * 64; s += 256) {
    const int d = s >> 6, i = s & 63;
    const float v = red[0][d][i] + red[1][d][i] + red[2][d][i] + red[3][d][i];
    atomicAdd(sEH + ((size_t)b * DD + d) * 64 + i, v);
  }
}

// ---------------- Kernel 2: main ----------------
// grid = N/8 = 1024 blocks, block = 512 (8 waves). One wave = one node; no barriers in main loop.
__global__ __launch_bounds__(512, 4) void k_main(
    const float* __restrict__ x, const float* __restrict__ emb,
    const float* __restrict__ mask, const float* __restrict__ wp,
    const float* __restrict__ bp, const int* __restrict__ np,
    const float* __restrict__ sEH, float* __restrict__ out) {
  __shared__ float E_l[8][DD];
  __shared__ float bb_l[8][64];
  __shared__ float mask_l[64][8];
  __shared__ __align__(16) bf16 Wt[8][64][72];  // [g][o][i], pad 72

  const int tid = threadIdx.x;
  const int lane = tid & 63;
  const int w = tid >> 6;          // wave = node index within block
  const int p0 = blockIdx.x * 8;   // base output position
  const int c = p0 >> 11;          // client

  // stage mask[64 b][8 g] and E[8 g][10 d]
  {
    const int bq = tid >> 3, g = tid & 7;
    mask_l[bq][g] = mask[(size_t)bq * NN + np[p0 + g]];
  }
  if (tid < 80) {
    const int g = tid / 10, d = tid % 10;
    E_l[g][d] = emb[(size_t)np[p0 + g] * DD + d];
  }
  __syncthreads();

  // W-build: wave w owns i in [w*8, w*8+8); lane = o. All 8 nodes at once.
  {
    f32x4 aLo[8], aHi[8];
#pragma unroll
    for (int p = 0; p < 8; ++p) { aLo[p] = (f32x4)0.f; aHi[p] = (f32x4)0.f; }
#pragma unroll
    for (int d = 0; d < DD; ++d) {
      f32x4 eLo, eHi;
      eLo[0] = E_l[0][d]; eLo[1] = E_l[1][d]; eLo[2] = E_l[2][d]; eLo[3] = E_l[3][d];
      eHi[0] = E_l[4][d]; eHi[1] = E_l[5][d]; eHi[2] = E_l[6][d]; eHi[3] = E_l[7][d];
      const float* base = wp + ((size_t)(c * DD + d) * 64 + w * 8) * 64 + lane;
#pragma unroll
      for (int p = 0; p < 8; ++p) {
        const float v = base[(size_t)p * 64];
        aLo[p] += eLo * v;
        aHi[p] += eHi * v;
      }
    }
#pragma unroll
    for (int g = 0; g < 8; ++g) {
      bf16x8 v;
#pragma unroll
      for (int p = 0; p < 8; ++p) v[p] = (bf16)((g < 4) ? aLo[p][g] : aHi[p][g - 4]);
      *(bf16x8*)&Wt[g][lane][w * 8] = v;
    }
    // bias for node w (lane = o)
    float bacc = 0.f;
#pragma unroll
    for (int d = 0; d < DD; ++d)
      bacc = fmaf(E_l[w][d], bp[((size_t)(c * DD + d)) * 64 + lane], bacc);
    bb_l[w][lane] = bacc;
  }
  __syncthreads();

  // per-wave state in registers
  const int mynode = np[p0 + w];
  const int q = lane >> 4, r16 = lane & 15;

  bf16x8 wfrag[4][2];
#pragma unroll
  for (int nt = 0; nt < 4; ++nt)
#pragma unroll
    for (int kt = 0; kt < 2; ++kt)
      wfrag[nt][kt] = *(const bf16x8*)&Wt[w][nt * 16 + r16][kt * 32 + q * 8];

  float biasv[4];
#pragma unroll
  for (int nt = 0; nt < 4; ++nt) biasv[nt] = bb_l[w][nt * 16 + r16];

  float tEr[DD];
#pragma unroll
  for (int d = 0; d < DD; ++d) tEr[d] = fmaxf(E_l[w][d], 0.f);

  const f32x4* x4 = (const f32x4*)x;
  const f32x4* s4 = (const f32x4*)sEH;

#pragma unroll
  for (int chunk = 0; chunk < 4; ++chunk) {
    const int b = chunk * 16 + r16;
    const float m = mask_l[b][w];
    const size_t xrow = ((size_t)b * NN + mynode) * 16;  // f32x4 units
    // z for (b=r16, i = kt*32 + q*8 + 0..7) -- exactly the MFMA A-frag layout
    f32x4 z00 = x4[xrow + q * 2 + 0] * m;
    f32x4 z01 = x4[xrow + q * 2 + 1] * m;
    f32x4 z10 = x4[xrow + 8 + q * 2 + 0] * m;
    f32x4 z11 = x4[xrow + 8 + q * 2 + 1] * m;
    const f32x4* sb = s4 + (size_t)b * DD * 16 + q * 2;
#pragma unroll
    for (int d = 0; d < DD; ++d) {
      const f32x4 s0 = sb[d * 16 + 0];
      const f32x4 s1 = sb[d * 16 + 1];
      const f32x4 s2 = sb[d * 16 + 8];
      const f32x4 s3 = sb[d * 16 + 9];
      const float t = tEr[d];
      z00 += s0 * t;
      z01 += s1 * t;
      z10 += s2 * t;
      z11 += s3 * t;
    }
    bf16x8 a0, a1;
#pragma unroll
    for (int j = 0; j < 4; ++j) {
      a0[j] = (bf16)z00[j];
      a0[4 + j] = (bf16)z01[j];
      a1[j] = (bf16)z10[j];
      a1[4 + j] = (bf16)z11[j];
    }
    f32x4 acc[4];
#pragma unroll
    for (int nt = 0; nt < 4; ++nt) {
      acc[nt][0] = biasv[nt]; acc[nt][1] = biasv[nt];
      acc[nt][2] = biasv[nt]; acc[nt][3] = biasv[nt];
    }
#pragma unroll
    for (int nt = 0; nt < 4; ++nt) {
      acc[nt] = __builtin_amdgcn_mfma_f32_16x16x32_bf16(a0, wfrag[nt][0], acc[nt], 0, 0, 0);
      acc[nt] = __builtin_amdgcn_mfma_f32_16x16x32_bf16(a1, wfrag[nt][1], acc[nt], 0, 0, 0);
    }
    // store: D row = q*4+r (b_loc), col = r16 (o within n-tile)
    const size_t pg = (size_t)(p0 + w);
#pragma unroll
    for (int nt = 0; nt < 4; ++nt) {
#pragma unroll
      for (int r = 0; r < 4; ++r) {
        const int bg = chunk * 16 + q * 4 + r;
        out[((size_t)bg * NN + pg) * 64 + nt * 16 + r16] = acc[nt][r];
      }
    }
  }
}

extern "C" void kernel_launch(void* const* d_in, const int* in_sizes, int n_in,
                              void* d_out, int out_size, void* d_ws, size_t ws_size,
                              hipStream_t stream) {
  const float* x    = (const float*)d_in[0];
  const float* emb  = (const float*)d_in[1];
  // d_in[2] = poly_coefficients (unused in sprtrelu mode)
  const float* mask = (const float*)d_in[3];
  const float* wp   = (const float*)d_in[4];
  const float* bp   = (const float*)d_in[5];
  const int*   np   = (const int*)d_in[6];
  float* out = (float*)d_out;
  float* sEH = (float*)d_ws;  // [64][10][64] f32 = 160 KB

  hipMemsetAsync(sEH, 0, (size_t)BB * DD * 64 * sizeof(float), stream);
  k_sumEH<<<dim3(BB * 16), dim3(256), 0, stream>>>(x, emb, mask, np, sEH);
  k_main<<<dim3(NN / 8), dim3(512), 0, stream>>>(x, emb, mask, wp, bp, np, sEH, out);
}

// Round 4
// 414.196 us; speedup vs baseline: 1.0566x; 1.0305x over previous
//
#include <hip/hip_runtime.h>
#include <hip/hip_bf16.h>

// AVWGCN: B=64, N=8192, Din=Dout=64, D=10, C=4, NPC=2048
// k1: sum_EH[b,d,i] = sum_n relu(E[n,d])*mask[b,n]*x[b,n,i]
//     lean streaming: float4 x-gathers (1KB/instr), uniform np/mask/emb gathers,
//     NO LDS staging, NO barriers in main loop, NO register arrays beyond acc.
// k2: one wave = one node (4 waves/block); W+bias built once in LDS (2 barriers total),
//     B-fragments + bias + tE hoisted to registers; barrier-free main loop;
//     z built in registers directly in MFMA A-frag layout (verified r1-r3);
//     mfma_f32_16x16x32_bf16, f32 stores.

#define BB 64
#define NN 8192
#define DD 10

typedef __bf16 bf16;
typedef __bf16 bf16x8 __attribute__((ext_vector_type(8)));
typedef float f32x4 __attribute__((ext_vector_type(4)));

// ---------------- Kernel 1: sum_EH ----------------
// grid = 64 b * 16 chunks (512 nodes each), block = 256 (4 waves)
__global__ __launch_bounds__(256, 2) void k_sumEH(
    const float* __restrict__ x, const float* __restrict__ emb,
    const float* __restrict__ mask, const int* __restrict__ np,
    float* __restrict__ sEH) {
  __shared__ __align__(16) float red[4][DD][64];

  const int b = blockIdx.x >> 4;
  const int chunk = blockIdx.x & 15;
  const int tid = threadIdx.x;
  const int lane = tid & 63;
  const int w = tid >> 6;
  const int qq = lane >> 4, r16 = lane & 15;

  const f32x4* x4 = (const f32x4*)(x + (size_t)b * NN * 64);
  const float* mb = mask + (size_t)b * NN;
  const int* npb = np + chunk * 512 + w * 128;

  f32x4 acc[DD];
#pragma unroll
  for (int d = 0; d < DD; ++d) acc[d] = (f32x4)0.f;

  // 32 groups; each instr: 4 nodes (qq) x 16 f32x4 (r16) = 1KB x-load
#pragma unroll 2
  for (int g = 0; g < 32; ++g) {
    const int idx = npb[g * 4 + qq];
    f32x4 xv = x4[(size_t)idx * 16 + r16];
    const float m = mb[idx];
    const float2* e2 = (const float2*)(emb + (size_t)idx * DD);
    const float2 e0 = e2[0], e1 = e2[1], e4 = e2[2], e6 = e2[3], e8 = e2[4];
    xv *= m;
    acc[0] += xv * fmaxf(e0.x, 0.f);
    acc[1] += xv * fmaxf(e0.y, 0.f);
    acc[2] += xv * fmaxf(e1.x, 0.f);
    acc[3] += xv * fmaxf(e1.y, 0.f);
    acc[4] += xv * fmaxf(e4.x, 0.f);
    acc[5] += xv * fmaxf(e4.y, 0.f);
    acc[6] += xv * fmaxf(e6.x, 0.f);
    acc[7] += xv * fmaxf(e6.y, 0.f);
    acc[8] += xv * fmaxf(e8.x, 0.f);
    acc[9] += xv * fmaxf(e8.y, 0.f);
  }

  // reduce across the 4 qq-groups (lanes l, l^16, l^32, l^48)
#pragma unroll
  for (int d = 0; d < DD; ++d) {
    f32x4 a = acc[d];
#pragma unroll
    for (int j = 0; j < 4; ++j) {
      float v = a[j];
      v += __shfl_xor(v, 16);
      v += __shfl_xor(v, 32);
      a[j] = v;
    }
    acc[d] = a;
  }
  if (qq == 0) {
#pragma unroll
    for (int d = 0; d < DD; ++d) *(f32x4*)&red[w][d][r16 * 4] = acc[d];
  }
  __syncthreads();

  for (int s = tid; s < DD * 64; s += 256) {
    const int d = s >> 6, i = s & 63;
    const float v = red[0][d][i] + red[1][d][i] + red[2][d][i] + red[3][d][i];
    atomicAdd(sEH + ((size_t)b * DD + d) * 64 + i, v);
  }
}

// ---------------- Kernel 2: main ----------------
// grid = N/4 = 2048 blocks, block = 256 (4 waves). One wave = one node.
__global__ __launch_bounds__(256, 2) void k_main(
    const float* __restrict__ x, const float* __restrict__ emb,
    const float* __restrict__ mask, const float* __restrict__ wp,
    const float* __restrict__ bp, const int* __restrict__ np,
    const float* __restrict__ sEH, float* __restrict__ out) {
  __shared__ float E_l[4][DD];
  __shared__ float bb_l[4][64];
  __shared__ float mask_l[64][4];
  __shared__ __align__(16) bf16 Wt[4][64][72];  // [g][o][i], pad 72

  const int tid = threadIdx.x;
  const int lane = tid & 63;
  const int w = tid >> 6;          // wave = node index within block
  const int p0 = blockIdx.x * 4;   // base output position
  const int c = p0 >> 11;          // client

  // stage mask[64 b][4 g] and E[4 g][10 d]
  {
    const int bq = tid >> 2, g = tid & 3;
    mask_l[bq][g] = mask[(size_t)bq * NN + np[p0 + g]];
  }
  if (tid < 40) {
    const int g = tid / 10, d = tid % 10;
    E_l[g][d] = emb[(size_t)np[p0 + g] * DD + d];
  }
  __syncthreads();

  // W-build: wave w owns i in [w*16, w*16+16); lane = o. All 4 nodes at once (pk-fma).
  {
    f32x4 accW[16];
#pragma unroll
    for (int p = 0; p < 16; ++p) accW[p] = (f32x4)0.f;
#pragma unroll
    for (int d = 0; d < DD; ++d) {
      f32x4 ev;
      ev[0] = E_l[0][d]; ev[1] = E_l[1][d]; ev[2] = E_l[2][d]; ev[3] = E_l[3][d];
      const float* base = wp + ((size_t)(c * DD + d) * 64 + w * 16) * 64 + lane;
#pragma unroll
      for (int p = 0; p < 16; ++p) accW[p] += ev * base[(size_t)p * 64];
    }
#pragma unroll
    for (int g = 0; g < 4; ++g) {
      bf16x8 v0, v1;
#pragma unroll
      for (int p = 0; p < 8; ++p) { v0[p] = (bf16)accW[p][g]; v1[p] = (bf16)accW[p + 8][g]; }
      *(bf16x8*)&Wt[g][lane][w * 16] = v0;
      *(bf16x8*)&Wt[g][lane][w * 16 + 8] = v1;
    }
    // bias for node w (lane = o)
    float bacc = 0.f;
#pragma unroll
    for (int d = 0; d < DD; ++d)
      bacc = fmaf(E_l[w][d], bp[((size_t)(c * DD + d)) * 64 + lane], bacc);
    bb_l[w][lane] = bacc;
  }
  __syncthreads();

  // per-wave state in registers
  const int mynode = np[p0 + w];
  const int q = lane >> 4, r16 = lane & 15;

  bf16x8 wfrag[4][2];
#pragma unroll
  for (int nt = 0; nt < 4; ++nt)
#pragma unroll
    for (int kt = 0; kt < 2; ++kt)
      wfrag[nt][kt] = *(const bf16x8*)&Wt[w][nt * 16 + r16][kt * 32 + q * 8];

  float biasv[4];
#pragma unroll
  for (int nt = 0; nt < 4; ++nt) biasv[nt] = bb_l[w][nt * 16 + r16];

  float tEr[DD];
#pragma unroll
  for (int d = 0; d < DD; ++d) tEr[d] = fmaxf(E_l[w][d], 0.f);

  const f32x4* x4 = (const f32x4*)x;
  const f32x4* s4 = (const f32x4*)sEH;

#pragma unroll
  for (int chunk = 0; chunk < 4; ++chunk) {
    const int b = chunk * 16 + r16;
    const float m = mask_l[b][w];
    const size_t xrow = ((size_t)b * NN + mynode) * 16;  // f32x4 units
    // z for (b=r16, i = kt*32 + q*8 + 0..7) -- exactly the MFMA A-frag layout
    f32x4 z00 = x4[xrow + q * 2 + 0] * m;
    f32x4 z01 = x4[xrow + q * 2 + 1] * m;
    f32x4 z10 = x4[xrow + 8 + q * 2 + 0] * m;
    f32x4 z11 = x4[xrow + 8 + q * 2 + 1] * m;
    const f32x4* sb = s4 + (size_t)b * DD * 16 + q * 2;
#pragma unroll
    for (int d = 0; d < DD; ++d) {
      const f32x4 s0 = sb[d * 16 + 0];
      const f32x4 s1 = sb[d * 16 + 1];
      const f32x4 s2 = sb[d * 16 + 8];
      const f32x4 s3 = sb[d * 16 + 9];
      const float t = tEr[d];
      z00 += s0 * t;
      z01 += s1 * t;
      z10 += s2 * t;
      z11 += s3 * t;
    }
    bf16x8 a0, a1;
#pragma unroll
    for (int j = 0; j < 4; ++j) {
      a0[j] = (bf16)z00[j];
      a0[4 + j] = (bf16)z01[j];
      a1[j] = (bf16)z10[j];
      a1[4 + j] = (bf16)z11[j];
    }
    f32x4 acc[4];
#pragma unroll
    for (int nt = 0; nt < 4; ++nt) {
      acc[nt][0] = biasv[nt]; acc[nt][1] = biasv[nt];
      acc[nt][2] = biasv[nt]; acc[nt][3] = biasv[nt];
    }
#pragma unroll
    for (int nt = 0; nt < 4; ++nt) {
      acc[nt] = __builtin_amdgcn_mfma_f32_16x16x32_bf16(a0, wfrag[nt][0], acc[nt], 0, 0, 0);
      acc[nt] = __builtin_amdgcn_mfma_f32_16x16x32_bf16(a1, wfrag[nt][1], acc[nt], 0, 0, 0);
    }
    // store: D row = q*4+r (b_loc), col = r16 (o within n-tile)
    const size_t pg = (size_t)(p0 + w);
#pragma unroll
    for (int nt = 0; nt < 4; ++nt) {
#pragma unroll
      for (int r = 0; r < 4; ++r) {
        const int bg = chunk * 16 + q * 4 + r;
        out[((size_t)bg * NN + pg) * 64 + nt * 16 + r16] = acc[nt][r];
      }
    }
  }
}

extern "C" void kernel_launch(void* const* d_in, const int* in_sizes, int n_in,
                              void* d_out, int out_size, void* d_ws, size_t ws_size,
                              hipStream_t stream) {
  const float* x    = (const float*)d_in[0];
  const float* emb  = (const float*)d_in[1];
  // d_in[2] = poly_coefficients (unused in sprtrelu mode)
  const float* mask = (const float*)d_in[3];
  const float* wp   = (const float*)d_in[4];
  const float* bp   = (const float*)d_in[5];
  const int*   np   = (const int*)d_in[6];
  float* out = (float*)d_out;
  float* sEH = (float*)d_ws;  // [64][10][64] f32 = 160 KB

  hipMemsetAsync(sEH, 0, (size_t)BB * DD * 64 * sizeof(float), stream);
  k_sumEH<<<dim3(BB * 16), dim3(256), 0, stream>>>(x, emb, mask, np, sEH);
  k_main<<<dim3(NN / 4), dim3(256), 0, stream>>>(x, emb, mask, wp, bp, np, sEH, out);
}